// Round 5
// baseline (104.446 us; speedup 1.0000x reference)
//
#include <hip/hip_runtime.h>

// Problem shape (fixed by reference setup_inputs):
//   bert_emb:    [B=4, Lp=256, D=768] fp32
//   pieces2word: [B=4, Lw=200, Lp=256] int32 (0/1)
//   out:         [B=4, Lw=200, D=768] fp32
// out[b,w,d] = max over {p : mask[b,w,p]!=0} of emb[b,p,d], else global min(emb).
//
// R4 design — PIECE-SCAN (loop inversion for reuse):
//  - Kernel 1 (build_bits): 800 wave-blocks ballot-compress p2w rows into
//    256-bit masks (4 u64 per word) in d_ws. ws is written before read every
//    call (harness re-poisons ws; we never read stale state).
//  - Kernel 2 (word_max_scan): block = 1 wave = (b, 64-float4 col chunk,
//    group of W=5 words). Each wave streams all 256 emb row-chunks ONCE,
//    merging into 5 register accumulators via WAVE-UNIFORM scalar branches
//    on the bitmasks (50% taken). Traffic: 480 waves x 256 KB = 123 MB of
//    L2 reads (vs 314 MB for gather) -- 2.5x cut; VALU only on active words.
//  - acc init = -inf (bit-exact: max is a selection; global min_value never
//    wins when any piece is active). Empty-mask word (P ~ 2^-256, never for
//    the fixed inputs) -> correct global-min fallback.

#define B_  4
#define LP_ 256
#define LW_ 200
#define D_  768
#define D4_ (D_ / 4)             // 192 float4 per row
#define CHUNKS 3                 // 3 chunks of 64 float4 columns
#define W_  5                    // words per wave
#define WG_ (LW_ / W_)           // 40 word-groups
#define NBLK2 (B_ * CHUNKS * WG_) // 480 blocks

// ---- Kernel 1: ballot-compress the 0/1 mask into 4 u64 per (b,w) ----
__global__ __launch_bounds__(64) void build_bits(
    const int* __restrict__ p2w, unsigned long long* __restrict__ bits)
{
    const int bw   = blockIdx.x;       // 0 .. B*Lw-1
    const int lane = threadIdx.x;
    const int* mrow = p2w + bw * LP_;
    #pragma unroll
    for (int r = 0; r < 4; ++r) {
        const unsigned long long bal = __ballot(mrow[r * 64 + lane] != 0);
        if (lane == 0) bits[bw * 4 + r] = bal;
    }
}

__device__ __forceinline__ float4 max4(float4 a, float4 b) {
    return make_float4(fmaxf(a.x, b.x), fmaxf(a.y, b.y),
                       fmaxf(a.z, b.z), fmaxf(a.w, b.w));
}

__device__ __forceinline__ unsigned long long uniform_u64(unsigned long long v) {
    // Force into SGPRs so mask tests become scalar branches.
    unsigned int lo = __builtin_amdgcn_readfirstlane((unsigned int)v);
    unsigned int hi = __builtin_amdgcn_readfirstlane((unsigned int)(v >> 32));
    return ((unsigned long long)hi << 32) | lo;
}

// ---- Kernel 2: piece-scan; 1 wave handles (b, chunk, 5 words) ----
__global__ __launch_bounds__(64) void word_max_scan(
    const float* __restrict__ emb, const unsigned long long* __restrict__ bits,
    float* __restrict__ out)
{
    const int blk   = blockIdx.x;          // 0..479
    const int wg    = blk % WG_;           // fastest: same (b,chunk) stream
    const int rest  = blk / WG_;
    const int chunk = rest % CHUNKS;
    const int b     = rest / CHUNKS;
    const int lane  = threadIdx.x;         // 0..63
    const int w0    = wg * W_;

    // Wave-uniform bitmask load (forced to SGPRs).
    unsigned long long m[W_][4];
    #pragma unroll
    for (int j = 0; j < W_; ++j) {
        const unsigned long long* mb = bits + (unsigned)((b * LW_ + w0 + j) * 4);
        #pragma unroll
        for (int r = 0; r < 4; ++r) m[j][r] = uniform_u64(mb[r]);
    }

    const float ninf = __uint_as_float(0xFF800000u);  // -inf
    float4 acc[W_];
    #pragma unroll
    for (int j = 0; j < W_; ++j) acc[j] = make_float4(ninf, ninf, ninf, ninf);

    const float4* rowp = (const float4*)(emb + b * LP_ * D_) + chunk * 64;

    // Stream all 256 piece rows once; merge under wave-uniform scalar branches.
    #pragma unroll
    for (int r = 0; r < 4; ++r) {
        unsigned long long mm[W_];
        #pragma unroll
        for (int j = 0; j < W_; ++j) mm[j] = m[j][r];
        for (int pp = 0; pp < 64; pp += 4) {
            const float4 v0 = rowp[lane];
            const float4 v1 = rowp[lane + 1 * D4_];
            const float4 v2 = rowp[lane + 2 * D4_];
            const float4 v3 = rowp[lane + 3 * D4_];
            rowp += 4 * D4_;
            #pragma unroll
            for (int j = 0; j < W_; ++j) {
                if (mm[j] & (1ull << (pp + 0))) acc[j] = max4(acc[j], v0);
                if (mm[j] & (1ull << (pp + 1))) acc[j] = max4(acc[j], v1);
                if (mm[j] & (1ull << (pp + 2))) acc[j] = max4(acc[j], v2);
                if (mm[j] & (1ull << (pp + 3))) acc[j] = max4(acc[j], v3);
            }
        }
    }

    // Epilogue: handle (never-taken) empty-mask words with the true global min.
    bool any_empty = false;
    #pragma unroll
    for (int j = 0; j < W_; ++j)
        if ((m[j][0] | m[j][1] | m[j][2] | m[j][3]) == 0ull) any_empty = true;

    float gmin = 0.0f;
    if (any_empty) {
        const float4* x = (const float4*)emb;
        const int n4 = (B_ * LP_ * D_) / 4;
        float mn = __uint_as_float(0x7F800000u);  // +inf
        for (int i = lane; i < n4; i += 64) {
            float4 v = x[i];
            mn = fminf(mn, fminf(fminf(v.x, v.y), fminf(v.z, v.w)));
        }
        #pragma unroll
        for (int off = 32; off > 0; off >>= 1)
            mn = fminf(mn, __shfl_down(mn, off, 64));
        gmin = __shfl(mn, 0, 64);
    }

    float4* obase = (float4*)out + (b * LW_ + w0) * D4_ + chunk * 64 + lane;
    #pragma unroll
    for (int j = 0; j < W_; ++j) {
        const bool empty = ((m[j][0] | m[j][1] | m[j][2] | m[j][3]) == 0ull);
        obase[j * D4_] = empty ? make_float4(gmin, gmin, gmin, gmin) : acc[j];
    }
}

extern "C" void kernel_launch(void* const* d_in, const int* in_sizes, int n_in,
                              void* d_out, int out_size, void* d_ws, size_t ws_size,
                              hipStream_t stream) {
    const float* emb = (const float*)d_in[0];
    const int*   p2w = (const int*)d_in[1];
    float*       out = (float*)d_out;
    unsigned long long* bits = (unsigned long long*)d_ws;  // 800*4*8 = 25.6 KB

    build_bits<<<B_ * LW_, 64, 0, stream>>>(p2w, bits);
    word_max_scan<<<NBLK2, 64, 0, stream>>>(emb, bits, out);
}

// Round 6
// 68.734 us; speedup vs baseline: 1.5196x; 1.5196x over previous
//
#include <hip/hip_runtime.h>

// Problem shape (fixed by reference setup_inputs):
//   bert_emb:    [B=4, Lp=256, D=768] fp32
//   pieces2word: [B=4, Lw=200, Lp=256] int32 (0/1)
//   out:         [B=4, Lw=200, D=768] fp32
// out[b,w,d] = max over {p : mask[b,w,p]!=0} of emb[b,p,d], else global min(emb).
//
// R5 design — branchless piece-scan, piece-segmented blocks:
//  - ONE kernel, no workspace. 960 blocks x 256 threads:
//    block = (b, chunk of 128 floats, group of W=5 words).
//    Wave s (0..3) owns piece segment [64s, 64s+64): it ballots its own
//    5 word-masks from p2w (no separate build kernel), streams its 64 emb
//    row-chunks ONCE, merging into 5 float2 accumulators BRANCHLESSLY:
//       acc = max2(acc, bit ? v : -inf)   // 2 cndmask + 2 max, no branches
//    VALU floor = B*Lw*Lp*D*2 = 315 M ops ~= 4.0 us; L2 traffic 123 MB
//    ~= 3.6 us, overlapped. 3.75 blocks/CU (vs R4's 1.9 waves/CU).
//  - End: LDS merge of the 4 segments (10.4 KB), float2 stores.
//  - acc init = -inf is bit-exact (max is a selection; min_value never wins
//    when any piece is active). Empty-mask word (P ~ 2^-256, never for the
//    fixed inputs) -> correct global-min fallback, never taken.

#define B_  4
#define LP_ 256
#define LW_ 200
#define D_  768
#define D2_ (D_ / 2)              // 384 float2 per row
#define CHUNKS 6                  // 6 chunks x 128 floats (1 float2 per lane)
#define W_  5                     // words per block
#define WG_ (LW_ / W_)            // 40 word-groups
#define NBLK (B_ * CHUNKS * WG_)  // 960 blocks

__device__ __forceinline__ float2 max2(float2 a, float2 b) {
    return make_float2(fmaxf(a.x, b.x), fmaxf(a.y, b.y));
}

__global__ __launch_bounds__(256) void word_max_scan(
    const float* __restrict__ emb, const int* __restrict__ p2w,
    float* __restrict__ out)
{
    const int blk   = blockIdx.x;
    const int wg    = blk % WG_;
    const int rest  = blk / WG_;
    const int chunk = rest % CHUNKS;
    const int b     = rest / CHUNKS;
    const int lane  = threadIdx.x & 63;
    const int s     = threadIdx.x >> 6;     // piece segment 0..3
    const int w0    = wg * W_;

    // Each wave ballots its own segment's bit-masks for the 5 words.
    unsigned long long m[W_];
    #pragma unroll
    for (int j = 0; j < W_; ++j) {
        const int* mrow = p2w + (b * LW_ + w0 + j) * LP_ + s * 64;
        m[j] = __ballot(mrow[lane] != 0);
    }

    const float ninf = __uint_as_float(0xFF800000u);
    const float2 n2 = make_float2(ninf, ninf);
    float2 acc[W_];
    #pragma unroll
    for (int j = 0; j < W_; ++j) acc[j] = n2;

    // Row pointer for this wave's segment; lane owns one float2 column pair.
    const float2* rp = (const float2*)(emb + (size_t)b * LP_ * D_ + chunk * 128)
                       + (size_t)(s * 64) * D2_ + lane;

    for (int pl = 0; pl < 64; pl += 4) {
        const float2 v0 = rp[(size_t)(pl + 0) * D2_];
        const float2 v1 = rp[(size_t)(pl + 1) * D2_];
        const float2 v2 = rp[(size_t)(pl + 2) * D2_];
        const float2 v3 = rp[(size_t)(pl + 3) * D2_];
        #pragma unroll
        for (int j = 0; j < W_; ++j) {
            acc[j] = max2(acc[j], ((m[j] >> (pl + 0)) & 1ull) ? v0 : n2);
            acc[j] = max2(acc[j], ((m[j] >> (pl + 1)) & 1ull) ? v1 : n2);
            acc[j] = max2(acc[j], ((m[j] >> (pl + 2)) & 1ull) ? v2 : n2);
            acc[j] = max2(acc[j], ((m[j] >> (pl + 3)) & 1ull) ? v3 : n2);
        }
    }

    // Merge the 4 segments via LDS.
    __shared__ float2 sacc[4][W_][64];
    __shared__ unsigned long long smask[4][W_];
    #pragma unroll
    for (int j = 0; j < W_; ++j) sacc[s][j][lane] = acc[j];
    if (lane == 0) {
        #pragma unroll
        for (int j = 0; j < W_; ++j) smask[s][j] = m[j];
    }
    __syncthreads();

    // Wave s finalizes words j with j % 4 == s (wave 0 also takes j=4).
    for (int j = s; j < W_; j += 4) {
        float2 r = max2(max2(sacc[0][j][lane], sacc[1][j][lane]),
                        max2(sacc[2][j][lane], sacc[3][j][lane]));
        const unsigned long long om =
            smask[0][j] | smask[1][j] | smask[2][j] | smask[3][j];
        if (om == 0ull) {
            // Never taken for the fixed inputs; correct fallback = global
            // min over ALL of emb (reference min_value semantics).
            const float4* x = (const float4*)emb;
            const int n4 = (B_ * LP_ * D_) / 4;
            float mn = __uint_as_float(0x7F800000u);  // +inf
            for (int i = lane; i < n4; i += 64) {
                float4 v = x[i];
                mn = fminf(mn, fminf(fminf(v.x, v.y), fminf(v.z, v.w)));
            }
            #pragma unroll
            for (int off = 32; off > 0; off >>= 1)
                mn = fminf(mn, __shfl_down(mn, off, 64));
            mn = __shfl(mn, 0, 64);
            r = make_float2(mn, mn);
        }
        float2* op = (float2*)(out + (size_t)(b * LW_ + w0 + j) * D_
                               + chunk * 128) + lane;
        *op = r;
    }
}

extern "C" void kernel_launch(void* const* d_in, const int* in_sizes, int n_in,
                              void* d_out, int out_size, void* d_ws, size_t ws_size,
                              hipStream_t stream) {
    const float* emb = (const float*)d_in[0];
    const int*   p2w = (const int*)d_in[1];
    float*       out = (float*)d_out;
    (void)d_ws; (void)ws_size;

    word_max_scan<<<NBLK, 256, 0, stream>>>(emb, p2w, out);
}

// Round 7
// 67.275 us; speedup vs baseline: 1.5525x; 1.0217x over previous
//
#include <hip/hip_runtime.h>

// Problem shape (fixed by reference setup_inputs):
//   bert_emb:    [B=4, Lp=256, D=768] fp32
//   pieces2word: [B=4, Lw=200, Lp=256] int32 (0/1)
//   out:         [B=4, Lw=200, D=768] fp32
// out[b,w,d] = max over {p : mask[b,w,p]!=0} of emb[b,p,d], else global min(emb).
//
// R6 design — branchless piece-scan, 8-way piece-split, guaranteed cndmask:
//  - ONE kernel, no workspace. 960 blocks x 512 threads (8 waves):
//    block = (b, chunk of 128 floats, group of W=5 words).
//    Wave s (0..7) owns pieces [32s, 32s+32): ballots its own 5x32-bit
//    word-masks from p2w, streams its 32 emb row-chunks once (unroll-8
//    dwordx2 loads), merges into 5 float2 accumulators with SCALAR-
//    component selects and IMMEDIATE bit tests:
//       acc.x = fmaxf(acc.x, bit ? v.x : -inf)   // v_cndmask + v_max
//    VALU floor ~4.5 us; L2 traffic 123 MB ~3.6 us (overlapped).
//    30 waves/CU (7.5/SIMD) vs R5's 15 (3.75/SIMD).
//  - End: LDS merge of 8 segments (20.5 KB), float2 stores.
//  - acc init = -inf is bit-exact (max is a selection; min_value never wins
//    when any piece is active). Empty-mask word (P ~ 2^-256, never for the
//    fixed inputs) -> correct global-min fallback, never taken.

#define B_  4
#define LP_ 256
#define LW_ 200
#define D_  768
#define D2_ (D_ / 2)              // 384 float2 per row
#define CHUNKS 6                  // 6 chunks x 128 floats (1 float2 per lane)
#define W_  5                     // words per block
#define WG_ (LW_ / W_)            // 40 word-groups
#define NBLK (B_ * CHUNKS * WG_)  // 960 blocks
#define SEGS 8                    // waves (piece segments) per block
#define PPS 32                    // pieces per segment

__global__ __launch_bounds__(512) void word_max_scan(
    const float* __restrict__ emb, const int* __restrict__ p2w,
    float* __restrict__ out)
{
    const int blk   = blockIdx.x;
    const int wg    = blk % WG_;
    const int rest  = blk / WG_;
    const int chunk = rest % CHUNKS;
    const int b     = rest / CHUNKS;
    const int lane  = threadIdx.x & 63;
    const int s     = threadIdx.x >> 6;     // piece segment 0..7
    const int w0    = wg * W_;

    // Each wave ballots a 32-bit mask for its 32 pieces, per word.
    // Lanes 0..31 test pieces 32s..32s+31; lanes 32..63 contribute 0.
    unsigned int m[W_];
    const int pc = s * PPS + (lane & 31);
    #pragma unroll
    for (int j = 0; j < W_; ++j) {
        const int* mrow = p2w + (b * LW_ + w0 + j) * LP_;
        m[j] = (unsigned int)__ballot((lane < 32) && (mrow[pc] != 0));
    }

    const float ninf = __uint_as_float(0xFF800000u);
    float2 acc[W_];
    #pragma unroll
    for (int j = 0; j < W_; ++j) acc[j] = make_float2(ninf, ninf);

    // Wave's row stream: rows [32s, 32s+32), column = chunk*64 + lane (float2).
    const float2* rps = (const float2*)(emb + (size_t)b * LP_ * D_)
                        + chunk * 64 + lane + (size_t)(s * PPS) * D2_;

    #pragma unroll
    for (int g = 0; g < PPS; g += 8) {
        float2 v[8];
        #pragma unroll
        for (int k = 0; k < 8; ++k)
            v[k] = rps[(size_t)(g + k) * D2_];
        #pragma unroll
        for (int k = 0; k < 8; ++k) {
            #pragma unroll
            for (int j = 0; j < W_; ++j) {
                const bool bit = (m[j] >> (g + k)) & 1u;  // immediate shift
                acc[j].x = fmaxf(acc[j].x, bit ? v[k].x : ninf);
                acc[j].y = fmaxf(acc[j].y, bit ? v[k].y : ninf);
            }
        }
    }

    // Merge the 8 segments via LDS.
    __shared__ float2 sacc[SEGS][W_][64];
    __shared__ unsigned int smask[SEGS][W_];
    #pragma unroll
    for (int j = 0; j < W_; ++j) sacc[s][j][lane] = acc[j];
    if (lane == 0) {
        #pragma unroll
        for (int j = 0; j < W_; ++j) smask[s][j] = m[j];
    }
    __syncthreads();

    // Wave j (< W_) finalizes word j.
    if (s < W_) {
        const int j = s;
        float2 r = sacc[0][j][lane];
        #pragma unroll
        for (int seg = 1; seg < SEGS; ++seg) {
            r.x = fmaxf(r.x, sacc[seg][j][lane].x);
            r.y = fmaxf(r.y, sacc[seg][j][lane].y);
        }
        unsigned int om = 0;
        #pragma unroll
        for (int seg = 0; seg < SEGS; ++seg) om |= smask[seg][j];

        if (om == 0u) {
            // Never taken for the fixed inputs; correct fallback = global
            // min over ALL of emb (reference min_value semantics).
            const float4* x = (const float4*)emb;
            const int n4 = (B_ * LP_ * D_) / 4;
            float mn = __uint_as_float(0x7F800000u);  // +inf
            for (int i = lane; i < n4; i += 64) {
                float4 vv = x[i];
                mn = fminf(mn, fminf(fminf(vv.x, vv.y), fminf(vv.z, vv.w)));
            }
            #pragma unroll
            for (int off = 32; off > 0; off >>= 1)
                mn = fminf(mn, __shfl_down(mn, off, 64));
            mn = __shfl(mn, 0, 64);
            r = make_float2(mn, mn);
        }

        float2* op = (float2*)out + (size_t)(b * LW_ + w0 + j) * D2_
                     + chunk * 64 + lane;
        *op = r;
    }
}

extern "C" void kernel_launch(void* const* d_in, const int* in_sizes, int n_in,
                              void* d_out, int out_size, void* d_ws, size_t ws_size,
                              hipStream_t stream) {
    const float* emb = (const float*)d_in[0];
    const int*   p2w = (const int*)d_in[1];
    float*       out = (float*)d_out;
    (void)d_ws; (void)ws_size;

    word_max_scan<<<NBLK, 512, 0, stream>>>(emb, p2w, out);
}